// Round 1
// baseline (343.986 us; speedup 1.0000x reference)
//
#include <hip/hip_runtime.h>
#include <hip/hip_bf16.h>

#define N_NODES 50000
#define N_EDGES 800000
#define IN_F 256
#define NH 4
#define DH 64
#define HD 256
#define ALPHA 0.2f

// ---------------- GEMM: ft = feat @ fc_w  (fp32, [M,256]x[256,256]) ----------------
// BM=64 BN=64 BK=16, 256 threads, 4x4 micro-tile per thread
__global__ __launch_bounds__(256) void k_gemm(const float* __restrict__ A,
                                              const float* __restrict__ B,
                                              float* __restrict__ C, int M) {
    __shared__ float As[16][64];
    __shared__ float Bs[16][64];
    const int tid = threadIdx.x;
    const int tx = tid & 15;        // n
    const int ty = tid >> 4;        // m
    const int m0 = blockIdx.x * 64;
    const int n0 = blockIdx.y * 64;

    // A-load mapping: row r = tid/4 (0..63), cols c4 = (tid%4)*4
    const int ar = tid >> 2;
    const int ac = (tid & 3) * 4;
    // B-load mapping: row r = tid/16 (0..15), cols c4 = (tid%16)*4
    const int br = tid >> 4;
    const int bc = (tid & 15) * 4;

    float acc[4][4] = {};

    for (int k0 = 0; k0 < IN_F; k0 += 16) {
        // load A tile (64 x 16), store transposed As[k][m]
        {
            int gm = m0 + ar;
            float4 v = make_float4(0.f, 0.f, 0.f, 0.f);
            if (gm < M) v = *(const float4*)&A[(size_t)gm * IN_F + k0 + ac];
            As[ac + 0][ar] = v.x;
            As[ac + 1][ar] = v.y;
            As[ac + 2][ar] = v.z;
            As[ac + 3][ar] = v.w;
        }
        // load B tile (16 x 64)
        {
            float4 v = *(const float4*)&B[(size_t)(k0 + br) * HD + n0 + bc];
            *(float4*)&Bs[br][bc] = v;
        }
        __syncthreads();
        #pragma unroll
        for (int k = 0; k < 16; k++) {
            float a0[4], b0[4];
            #pragma unroll
            for (int i = 0; i < 4; i++) a0[i] = As[k][ty * 4 + i];
            #pragma unroll
            for (int j = 0; j < 4; j++) b0[j] = Bs[k][tx * 4 + j];
            #pragma unroll
            for (int i = 0; i < 4; i++)
                #pragma unroll
                for (int j = 0; j < 4; j++)
                    acc[i][j] = fmaf(a0[i], b0[j], acc[i][j]);
        }
        __syncthreads();
    }
    #pragma unroll
    for (int i = 0; i < 4; i++) {
        int gm = m0 + ty * 4 + i;
        if (gm < M) {
            float4 v = make_float4(acc[i][0], acc[i][1], acc[i][2], acc[i][3]);
            *(float4*)&C[(size_t)gm * HD + n0 + tx * 4] = v;
        }
    }
}

// ---------------- el/er: per-node attention logits ----------------
__global__ __launch_bounds__(256) void k_elr(const float* __restrict__ ft,
                                             const float* __restrict__ al,
                                             const float* __restrict__ ar,
                                             float* __restrict__ el,
                                             float* __restrict__ er, int N) {
    int wid = (blockIdx.x * blockDim.x + threadIdx.x) >> 6;
    int lane = threadIdx.x & 63;
    if (wid >= N) return;
    const float* f = ft + (size_t)wid * HD;
    #pragma unroll
    for (int h = 0; h < NH; h++) {
        float v = f[h * DH + lane];
        float pl = v * al[h * DH + lane];
        float pr = v * ar[h * DH + lane];
        #pragma unroll
        for (int off = 32; off; off >>= 1) {
            pl += __shfl_down(pl, off);
            pr += __shfl_down(pr, off);
        }
        if (lane == 0) {
            el[wid * NH + h] = pl;
            er[wid * NH + h] = pr;
        }
    }
}

// ---------------- CSR build ----------------
__global__ __launch_bounds__(256) void k_hist(const int* __restrict__ dst, int* __restrict__ counts) {
    int e = blockIdx.x * blockDim.x + threadIdx.x;
    if (e < N_EDGES) atomicAdd(&counts[dst[e]], 1);
}

__global__ __launch_bounds__(512) void k_scan1(const int* __restrict__ counts,
                                               int* __restrict__ incl,
                                               int* __restrict__ bsum, int N) {
    __shared__ int sm[512];
    int i = blockIdx.x * 512 + threadIdx.x;
    int v = (i < N) ? counts[i] : 0;
    sm[threadIdx.x] = v;
    __syncthreads();
    for (int off = 1; off < 512; off <<= 1) {
        int t = (threadIdx.x >= off) ? sm[threadIdx.x - off] : 0;
        __syncthreads();
        sm[threadIdx.x] += t;
        __syncthreads();
    }
    if (i < N) incl[i] = sm[threadIdx.x];
    if (threadIdx.x == 511) bsum[blockIdx.x] = sm[511];
}

__global__ __launch_bounds__(128) void k_scan2(int* __restrict__ bsum, int nb) {
    __shared__ int sm[128];
    int v = (threadIdx.x < nb) ? bsum[threadIdx.x] : 0;
    sm[threadIdx.x] = v;
    __syncthreads();
    for (int off = 1; off < 128; off <<= 1) {
        int t = (threadIdx.x >= off) ? sm[threadIdx.x - off] : 0;
        __syncthreads();
        sm[threadIdx.x] += t;
        __syncthreads();
    }
    if (threadIdx.x < nb) bsum[threadIdx.x] = sm[threadIdx.x] - v;  // exclusive
}

__global__ __launch_bounds__(256) void k_scan3(const int* __restrict__ counts,
                                               const int* __restrict__ incl,
                                               const int* __restrict__ bsum,
                                               int* __restrict__ offs,
                                               int* __restrict__ cursor, int N) {
    int i = blockIdx.x * blockDim.x + threadIdx.x;
    if (i < N) {
        int o = incl[i] - counts[i] + bsum[i >> 9];
        offs[i] = o;
        cursor[i] = o;
    }
}

__global__ __launch_bounds__(256) void k_scatter(const int* __restrict__ src,
                                                 const int* __restrict__ dst,
                                                 int* __restrict__ cursor,
                                                 int* __restrict__ esrc) {
    int e = blockIdx.x * blockDim.x + threadIdx.x;
    if (e < N_EDGES) {
        int p = atomicAdd(&cursor[dst[e]], 1);
        esrc[p] = src[e];
    }
}

// ---------------- Aggregation: one wave per destination node ----------------
__global__ __launch_bounds__(256) void k_agg(const float* __restrict__ ft,
                                             const float* __restrict__ el,
                                             const float* __restrict__ er,
                                             const int* __restrict__ offs,
                                             const int* __restrict__ counts,
                                             const int* __restrict__ esrc,
                                             float* __restrict__ out, int N) {
    int wid = (blockIdx.x * blockDim.x + threadIdx.x) >> 6;
    int lane = threadIdx.x & 63;
    if (wid >= N) return;
    const int v = wid;
    const int deg = counts[v];
    const int start = offs[v];

    float erh[NH];
    #pragma unroll
    for (int h = 0; h < NH; h++) erh[h] = er[v * NH + h];

    // pass 1: softmax denominators (lane-parallel over edges)
    float s[NH] = {0.f, 0.f, 0.f, 0.f};
    for (int i = lane; i < deg; i += 64) {
        int sv = esrc[start + i];
        #pragma unroll
        for (int h = 0; h < NH; h++) {
            float x = el[sv * NH + h] + erh[h];
            x = (x > 0.f) ? x : ALPHA * x;
            s[h] += __expf(x);
        }
    }
    #pragma unroll
    for (int h = 0; h < NH; h++)
        #pragma unroll
        for (int off = 32; off; off >>= 1) s[h] += __shfl_xor(s[h], off);

    float inv[NH];
    #pragma unroll
    for (int h = 0; h < NH; h++) inv[h] = (s[h] > 0.f) ? 1.f / s[h] : 0.f;

    // pass 2: weighted gather-accumulate; lane owns column d = lane
    float acc[NH] = {0.f, 0.f, 0.f, 0.f};
    for (int i = 0; i < deg; i++) {
        int sv = esrc[start + i];                 // wave-uniform
        const float* fp = ft + (size_t)sv * HD;
        #pragma unroll
        for (int h = 0; h < NH; h++) {
            float x = el[sv * NH + h] + erh[h];   // broadcast load
            x = (x > 0.f) ? x : ALPHA * x;
            float a = __expf(x) * inv[h];
            acc[h] = fmaf(a, fp[h * DH + lane], acc[h]);
        }
    }
    #pragma unroll
    for (int h = 0; h < NH; h++) out[(size_t)v * HD + h * DH + lane] = acc[h];
}

// ---------------- launch ----------------
extern "C" void kernel_launch(void* const* d_in, const int* in_sizes, int n_in,
                              void* d_out, int out_size, void* d_ws, size_t ws_size,
                              hipStream_t stream) {
    const float* feat = (const float*)d_in[0];
    const float* fc_w = (const float*)d_in[1];
    const float* attn_l = (const float*)d_in[2];
    const float* attn_r = (const float*)d_in[3];
    const int* src = (const int*)d_in[4];
    const int* dst = (const int*)d_in[5];
    float* out = (float*)d_out;

    char* w = (char*)d_ws;
    float* ft = (float*)w;      w += (size_t)N_NODES * HD * sizeof(float);   // 51.2 MB
    float* el = (float*)w;      w += (size_t)N_NODES * NH * sizeof(float);
    float* er = (float*)w;      w += (size_t)N_NODES * NH * sizeof(float);
    int* counts = (int*)w;      w += (size_t)N_NODES * sizeof(int);
    int* incl = (int*)w;        w += (size_t)N_NODES * sizeof(int);
    int* offs = (int*)w;        w += (size_t)N_NODES * sizeof(int);
    int* cursor = (int*)w;      w += (size_t)N_NODES * sizeof(int);
    int* bsum = (int*)w;        w += 1024;
    int* esrc = (int*)w;        w += (size_t)N_EDGES * sizeof(int);

    hipMemsetAsync(counts, 0, N_NODES * sizeof(int), stream);

    // GEMM: grid (ceil(M/64), 256/64)
    dim3 ggrid((N_NODES + 63) / 64, HD / 64);
    k_gemm<<<ggrid, 256, 0, stream>>>(feat, fc_w, ft, N_NODES);

    // el / er
    int elr_blocks = (N_NODES * 64 + 255) / 256;
    k_elr<<<elr_blocks, 256, 0, stream>>>(ft, attn_l, attn_r, el, er, N_NODES);

    // CSR build
    int eblocks = (N_EDGES + 255) / 256;
    k_hist<<<eblocks, 256, 0, stream>>>(dst, counts);
    int nsb = (N_NODES + 511) / 512;                       // 98
    k_scan1<<<nsb, 512, 0, stream>>>(counts, incl, bsum, N_NODES);
    k_scan2<<<1, 128, 0, stream>>>(bsum, nsb);
    k_scan3<<<(N_NODES + 255) / 256, 256, 0, stream>>>(counts, incl, bsum, offs, cursor, N_NODES);
    k_scatter<<<eblocks, 256, 0, stream>>>(src, dst, cursor, esrc);

    // aggregation
    int agg_blocks = (N_NODES * 64 + 255) / 256;
    k_agg<<<agg_blocks, 256, 0, stream>>>(ft, el, er, offs, counts, esrc, out, N_NODES);
}

// Round 2
// 204.651 us; speedup vs baseline: 1.6808x; 1.6808x over previous
//
#include <hip/hip_runtime.h>
#include <hip/hip_bf16.h>

#define N_NODES 50000
#define N_EDGES 800000
#define IN_F 256
#define NH 4
#define DH 64
#define HD 256
#define ALPHA 0.2f

typedef short bf16x8 __attribute__((ext_vector_type(8)));
typedef float f32x4 __attribute__((ext_vector_type(4)));

__device__ __forceinline__ unsigned short f2bf(float f) {
    unsigned u = __float_as_uint(f);
    u = (u + 0x7FFFu + ((u >> 16) & 1u)) >> 16;   // RNE
    return (unsigned short)u;
}
__device__ __forceinline__ float bf2f(unsigned short h) {
    return __uint_as_float(((unsigned)h) << 16);
}

// ---------------- fc_w [k][n] fp32 -> Bt [n][k] bf16 (transpose + convert) ----------
__global__ __launch_bounds__(256) void k_cvt_w(const float* __restrict__ fw,
                                               unsigned short* __restrict__ Bt) {
    int n = blockIdx.x;            // 0..255
    int k = threadIdx.x;           // 0..255
    Bt[n * 256 + k] = f2bf(fw[k * 256 + n]);
}

// ---------------- GEMM: ftb = bf16( feat @ fc_w ), MFMA 16x16x32 ----------------
// BM=128 BN=128, 512 threads (8 waves), grid (2, ceil(M/128))
__global__ __launch_bounds__(512, 4) void k_gemm(const float* __restrict__ A,
                                                 const unsigned short* __restrict__ Bt,
                                                 unsigned short* __restrict__ ftb, int M) {
    __shared__ __align__(16) char smem[66048];   // 64KB swizzled B-tile, reused as 128x129 f32 epilogue
    const int tid = threadIdx.x;
    const int n0 = blockIdx.x * 128;
    const int m0 = blockIdx.y * 128;

    // stage Bt[n0..n0+127][0..255] into LDS, XOR-swizzled on 16B granularity
    {
        int nl = tid >> 2, q = tid & 3;
        const unsigned short* srow = Bt + (size_t)(n0 + nl) * 256 + q * 64;
        #pragma unroll
        for (int c = 0; c < 8; c++) {
            bf16x8 v = *(const bf16x8*)(srow + c * 8);
            int lb = nl * 512 + q * 128 + c * 16;
            lb ^= (nl & 7) << 4;
            *(bf16x8*)(smem + lb) = v;
        }
    }
    __syncthreads();

    const int w = tid >> 6, lane = tid & 63;
    const int fr = lane & 15, quad = lane >> 4;
    int gm = m0 + w * 16 + fr;
    const float* arow = A + (size_t)(gm < M ? gm : 0) * IN_F;

    f32x4 acc[8];
    #pragma unroll
    for (int f = 0; f < 8; f++) acc[f] = (f32x4){0.f, 0.f, 0.f, 0.f};

    #pragma unroll
    for (int kk = 0; kk < 8; kk++) {
        float4 lo = *(const float4*)(arow + kk * 32 + quad * 8);
        float4 hi = *(const float4*)(arow + kk * 32 + quad * 8 + 4);
        bf16x8 af;
        af[0] = (short)f2bf(lo.x); af[1] = (short)f2bf(lo.y);
        af[2] = (short)f2bf(lo.z); af[3] = (short)f2bf(lo.w);
        af[4] = (short)f2bf(hi.x); af[5] = (short)f2bf(hi.y);
        af[6] = (short)f2bf(hi.z); af[7] = (short)f2bf(hi.w);
        #pragma unroll
        for (int f = 0; f < 8; f++) {
            int nl = f * 16 + fr;
            int lb = nl * 512 + (kk * 32 + quad * 8) * 2;
            lb ^= (nl & 7) << 4;
            bf16x8 bfr = *(const bf16x8*)(smem + lb);
            acc[f] = __builtin_amdgcn_mfma_f32_16x16x32_bf16(af, bfr, acc[f], 0, 0, 0);
        }
    }
    __syncthreads();   // done reading B LDS

    // epilogue bounce: C/D layout col=lane&15, row=quad*4+reg
    float* eb = (float*)smem;
    #pragma unroll
    for (int f = 0; f < 8; f++)
        #pragma unroll
        for (int r = 0; r < 4; r++)
            eb[(w * 16 + quad * 4 + r) * 129 + f * 16 + fr] = acc[f][r];
    __syncthreads();

    {
        int r = tid >> 2, cs = (tid & 3) * 32;
        int gr = m0 + r;
        if (gr < M) {
            unsigned short tmp[32];
            #pragma unroll
            for (int i = 0; i < 32; i++) tmp[i] = f2bf(eb[r * 129 + cs + i]);
            unsigned short* dp = ftb + (size_t)gr * HD + n0 + cs;
            #pragma unroll
            for (int c = 0; c < 4; c++)
                *(bf16x8*)(dp + c * 8) = *(const bf16x8*)(tmp + c * 8);
        }
    }
}

// ---------------- el/er from bf16 ft: one wave per node ----------------
__global__ __launch_bounds__(256) void k_elr(const unsigned short* __restrict__ ftb,
                                             const float* __restrict__ al,
                                             const float* __restrict__ ar,
                                             float* __restrict__ el,
                                             float* __restrict__ er, int N) {
    int wid = (blockIdx.x * 256 + threadIdx.x) >> 6;
    int lane = threadIdx.x & 63;
    if (wid >= N) return;
    ushort4 fv = ((const ushort4*)ftb)[(size_t)wid * 64 + lane];
    float4 a4 = ((const float4*)al)[lane];
    float4 b4 = ((const float4*)ar)[lane];
    float f0 = bf2f(fv.x), f1 = bf2f(fv.y), f2 = bf2f(fv.z), f3 = bf2f(fv.w);
    float pl = f0 * a4.x + f1 * a4.y + f2 * a4.z + f3 * a4.w;
    float pr = f0 * b4.x + f1 * b4.y + f2 * b4.z + f3 * b4.w;
    #pragma unroll
    for (int off = 1; off < 16; off <<= 1) {
        pl += __shfl_xor(pl, off);
        pr += __shfl_xor(pr, off);
    }
    if ((lane & 15) == 0) {
        el[wid * NH + (lane >> 4)] = pl;
        er[wid * NH + (lane >> 4)] = pr;
    }
}

// ---------------- CSR build ----------------
__global__ __launch_bounds__(256) void k_hist(const int* __restrict__ dst, int* __restrict__ counts) {
    int e = blockIdx.x * blockDim.x + threadIdx.x;
    if (e < N_EDGES) atomicAdd(&counts[dst[e]], 1);
}

__global__ __launch_bounds__(512) void k_scan1(const int* __restrict__ counts,
                                               int* __restrict__ incl,
                                               int* __restrict__ bsum, int N) {
    __shared__ int sm[512];
    int i = blockIdx.x * 512 + threadIdx.x;
    int v = (i < N) ? counts[i] : 0;
    sm[threadIdx.x] = v;
    __syncthreads();
    for (int off = 1; off < 512; off <<= 1) {
        int t = (threadIdx.x >= off) ? sm[threadIdx.x - off] : 0;
        __syncthreads();
        sm[threadIdx.x] += t;
        __syncthreads();
    }
    if (i < N) incl[i] = sm[threadIdx.x];
    if (threadIdx.x == 511) bsum[blockIdx.x] = sm[511];
}

__global__ __launch_bounds__(128) void k_scan2(int* __restrict__ bsum, int nb) {
    __shared__ int sm[128];
    int v = (threadIdx.x < nb) ? bsum[threadIdx.x] : 0;
    sm[threadIdx.x] = v;
    __syncthreads();
    for (int off = 1; off < 128; off <<= 1) {
        int t = (threadIdx.x >= off) ? sm[threadIdx.x - off] : 0;
        __syncthreads();
        sm[threadIdx.x] += t;
        __syncthreads();
    }
    if (threadIdx.x < nb) bsum[threadIdx.x] = sm[threadIdx.x] - v;  // exclusive
}

__global__ __launch_bounds__(256) void k_scan3(const int* __restrict__ counts,
                                               const int* __restrict__ incl,
                                               const int* __restrict__ bsum,
                                               int* __restrict__ offs,
                                               int* __restrict__ cursor, int N) {
    int i = blockIdx.x * blockDim.x + threadIdx.x;
    if (i < N) {
        int o = incl[i] - counts[i] + bsum[i >> 9];
        offs[i] = o;
        cursor[i] = o;
    }
}

// ---------------- scatter + per-edge softmax numerator (CSR order) ----------------
__global__ __launch_bounds__(256) void k_scatter(const int* __restrict__ src,
                                                 const int* __restrict__ dst,
                                                 int* __restrict__ cursor,
                                                 int* __restrict__ esrc,
                                                 const float* __restrict__ el,
                                                 const float* __restrict__ er,
                                                 float* __restrict__ wbuf) {
    int e = blockIdx.x * blockDim.x + threadIdx.x;
    if (e >= N_EDGES) return;
    int s = src[e], d = dst[e];
    int p = atomicAdd(&cursor[d], 1);
    esrc[p] = s;
    float4 l4 = ((const float4*)el)[s];
    float4 r4 = ((const float4*)er)[d];
    float4 we;
    float x;
    x = l4.x + r4.x; x = (x > 0.f) ? x : ALPHA * x; we.x = __expf(x);
    x = l4.y + r4.y; x = (x > 0.f) ? x : ALPHA * x; we.y = __expf(x);
    x = l4.z + r4.z; x = (x > 0.f) ? x : ALPHA * x; we.z = __expf(x);
    x = l4.w + r4.w; x = (x > 0.f) ? x : ALPHA * x; we.w = __expf(x);
    ((float4*)wbuf)[p] = we;
}

// ---------------- Aggregation: one wave per destination node ----------------
__global__ __launch_bounds__(256) void k_agg(const unsigned short* __restrict__ ftb,
                                             const float* __restrict__ wbuf,
                                             const int* __restrict__ offs,
                                             const int* __restrict__ counts,
                                             const int* __restrict__ esrc,
                                             float* __restrict__ out, int N) {
    int wid = (blockIdx.x * 256 + threadIdx.x) >> 6;
    int lane = threadIdx.x & 63;
    if (wid >= N) return;
    const int deg = counts[wid];
    const int start = offs[wid];
    const int quad = lane >> 4;

    // pass 1: denominators (contiguous, L2-resident)
    float sx = 0.f, sy = 0.f, sz = 0.f, sw = 0.f;
    for (int i = lane; i < deg; i += 64) {
        float4 ww = ((const float4*)wbuf)[start + i];
        sx += ww.x; sy += ww.y; sz += ww.z; sw += ww.w;
    }
    #pragma unroll
    for (int off = 1; off < 64; off <<= 1) {
        sx += __shfl_xor(sx, off);
        sy += __shfl_xor(sy, off);
        sz += __shfl_xor(sz, off);
        sw += __shfl_xor(sw, off);
    }
    float sh = (quad == 0) ? sx : (quad == 1) ? sy : (quad == 2) ? sz : sw;
    float inv = (sh > 0.f) ? 1.f / sh : 0.f;

    // pass 2: weighted gather-accumulate; lane owns 4 consecutive cols (one head)
    float a0 = 0.f, a1 = 0.f, a2 = 0.f, a3 = 0.f;
    #pragma unroll 4
    for (int i = 0; i < deg; i++) {
        int sv = esrc[start + i];
        float we = wbuf[(size_t)(start + i) * 4 + quad];
        ushort4 fv = ((const ushort4*)ftb)[(size_t)sv * 64 + lane];
        a0 = fmaf(we, bf2f(fv.x), a0);
        a1 = fmaf(we, bf2f(fv.y), a1);
        a2 = fmaf(we, bf2f(fv.z), a2);
        a3 = fmaf(we, bf2f(fv.w), a3);
    }
    float4 o = make_float4(a0 * inv, a1 * inv, a2 * inv, a3 * inv);
    ((float4*)out)[(size_t)wid * 64 + lane] = o;
}

// ---------------- launch ----------------
extern "C" void kernel_launch(void* const* d_in, const int* in_sizes, int n_in,
                              void* d_out, int out_size, void* d_ws, size_t ws_size,
                              hipStream_t stream) {
    const float* feat = (const float*)d_in[0];
    const float* fc_w = (const float*)d_in[1];
    const float* attn_l = (const float*)d_in[2];
    const float* attn_r = (const float*)d_in[3];
    const int* src = (const int*)d_in[4];
    const int* dst = (const int*)d_in[5];
    float* out = (float*)d_out;

    char* w = (char*)d_ws;
    unsigned short* ftb = (unsigned short*)w;  w += (size_t)N_NODES * HD * 2;      // 25.6 MB
    unsigned short* Bt = (unsigned short*)w;   w += (size_t)IN_F * HD * 2;         // 128 KB
    float* el = (float*)w;       w += (size_t)N_NODES * NH * 4;
    float* er = (float*)w;       w += (size_t)N_NODES * NH * 4;
    int* counts = (int*)w;       w += (size_t)N_NODES * 4;
    int* incl = (int*)w;         w += (size_t)N_NODES * 4;
    int* offs = (int*)w;         w += (size_t)N_NODES * 4;
    int* cursor = (int*)w;       w += (size_t)N_NODES * 4;
    int* bsum = (int*)w;         w += 1024;
    int* esrc = (int*)w;         w += (size_t)N_EDGES * 4;                          // 3.2 MB
    float* wbuf = (float*)w;     w += (size_t)N_EDGES * NH * 4;                     // 12.8 MB

    hipMemsetAsync(counts, 0, N_NODES * sizeof(int), stream);

    k_cvt_w<<<256, 256, 0, stream>>>(fc_w, Bt);

    dim3 ggrid(HD / 128, (N_NODES + 127) / 128);   // n-split fast dim -> A rows reused in L2
    k_gemm<<<ggrid, 512, 0, stream>>>(feat, Bt, ftb, N_NODES);

    int elr_blocks = (N_NODES * 64 + 255) / 256;
    k_elr<<<elr_blocks, 256, 0, stream>>>(ftb, attn_l, attn_r, el, er, N_NODES);

    int eblocks = (N_EDGES + 255) / 256;
    k_hist<<<eblocks, 256, 0, stream>>>(dst, counts);
    int nsb = (N_NODES + 511) / 512;
    k_scan1<<<nsb, 512, 0, stream>>>(counts, incl, bsum, N_NODES);
    k_scan2<<<1, 128, 0, stream>>>(bsum, nsb);
    k_scan3<<<(N_NODES + 255) / 256, 256, 0, stream>>>(counts, incl, bsum, offs, cursor, N_NODES);
    k_scatter<<<eblocks, 256, 0, stream>>>(src, dst, cursor, esrc, el, er, wbuf);

    int agg_blocks = (N_NODES * 64 + 255) / 256;
    k_agg<<<agg_blocks, 256, 0, stream>>>(ftb, wbuf, offs, counts, esrc, out, N_NODES);
}